// Round 9
// baseline (74.230 us; speedup 1.0000x reference)
//
#include <hip/hip_runtime.h>

typedef __attribute__((ext_vector_type(4))) float f32x4;
typedef __attribute__((ext_vector_type(16))) float f32x16;
typedef __attribute__((ext_vector_type(8))) __bf16 bf16x8;
typedef __attribute__((ext_vector_type(4))) __bf16 bf16x4;

#define L_SEQ 1024
#define NB 8
#define EMB 256
#define NHEAD 8
#define HD 32
#define MROWS 8192  // L_SEQ * NB
#define SZ_ELEM ((size_t)MROWS * EMB)

static __device__ __forceinline__ f32x4 mfma_bf16(bf16x8 a, bf16x8 b, f32x4 c) {
    return __builtin_amdgcn_mfma_f32_16x16x32_bf16(a, b, c, 0, 0, 0);
}
static __device__ __forceinline__ f32x16 mfma32(bf16x8 a, bf16x8 b, f32x16 c) {
    return __builtin_amdgcn_mfma_f32_32x32x16_bf16(a, b, c, 0, 0, 0);
}

// Scalar bf16 pack (PROVEN R1-R4/R6/R8; do NOT replace with v_cvt_pk_bf16_f32
// asm — R7 failed with it: element-order mismatch).
static __device__ __forceinline__ unsigned pack2(float a, float b) {
    union { __bf16 h; unsigned short u; } lo, hi;
    lo.h = (__bf16)a; hi.h = (__bf16)b;
    return (unsigned)lo.u | ((unsigned)hi.u << 16);
}

// v_permlane32_swap_b32: a.hi-half-lanes <-> b.lo-half-lanes (R4/R6/R8-proven)
static __device__ __forceinline__ void permswap(unsigned &a, unsigned &b) {
    asm("v_permlane32_swap_b32 %0, %1" : "+v"(a), "+v"(b));
}

struct GemmBatch {
    const void* X[6];
    const float* W[6];
    const float* Bv[6];
    void* O[6];
    float scale[6];
};

// C[m,n] = (sum_k X[m,k] * W[n,k] + bias[n]) * scale
// BM=128, BN=64, BK=64, 256 threads = 4 waves (2x2), each wave 64x32.
// XMODE: 0 = f32 X, 1 = bf16 X.
template<int XMODE, bool OUT_F32>
__global__ __launch_bounds__(256, 2)
void gemm_kernel(GemmBatch batch) {
    __shared__ __bf16 Xl[128][72];
    __shared__ __bf16 Wl[64][72];
    const int z = blockIdx.z;
    const int fid = blockIdx.x;
    const int swz = (fid & 7) * 32 + (fid >> 3);   // 256 blocks -> 8 XCD chunks of 32
    const int nblk = swz & 3, mblk = swz >> 2;
    const float* __restrict__ W = batch.W[z];
    const float* __restrict__ bias = batch.Bv[z];
    const float scale = batch.scale[z];
    const int tid = threadIdx.x;
    const int w = tid >> 6, lane = tid & 63;
    const int g = lane >> 4, li = lane & 15;
    const int wr = w >> 1, wc = w & 1;

    f32x4 acc[4][2];
#pragma unroll
    for (int i = 0; i < 4; ++i)
#pragma unroll
        for (int j = 0; j < 2; ++j) acc[i][j] = f32x4{0.f, 0.f, 0.f, 0.f};

    for (int kk = 0; kk < 4; ++kk) {
        __syncthreads();
        if (XMODE == 1) {
            const __bf16* Xb = (const __bf16*)batch.X[z];
#pragma unroll
            for (int p = 0; p < 4; ++p) {
                int idx = tid + p * 256;
                int row = idx >> 3, c8 = (idx & 7) * 8;
                bf16x8 xv = *(const bf16x8*)(Xb + (size_t)(mblk * 128 + row) * 256 + kk * 64 + c8);
                *(bf16x8*)&Xl[row][c8] = xv;
            }
        } else {
            const float* Xf = (const float*)batch.X[z];
#pragma unroll
            for (int p = 0; p < 8; ++p) {
                int idx = tid + p * 256;
                int row = idx >> 4, c4 = (idx & 15) * 4;
                f32x4 xv = *(const f32x4*)(Xf + (size_t)(mblk * 128 + row) * 256 + kk * 64 + c4);
                bf16x4 bv;
#pragma unroll
                for (int j = 0; j < 4; ++j) bv[j] = (__bf16)xv[j];
                *(bf16x4*)&Xl[row][c4] = bv;
            }
        }
#pragma unroll
        for (int p = 0; p < 4; ++p) {
            int idx = tid + p * 256;
            int row = idx >> 4, c4 = (idx & 15) * 4;
            f32x4 wv = *(const f32x4*)(W + (size_t)(nblk * 64 + row) * 256 + kk * 64 + c4);
            bf16x4 bv;
#pragma unroll
            for (int j = 0; j < 4; ++j) bv[j] = (__bf16)wv[j];
            *(bf16x4*)&Wl[row][c4] = bv;
        }
        __syncthreads();
#pragma unroll
        for (int ks = 0; ks < 2; ++ks) {
            bf16x8 a[4], b[2];
#pragma unroll
            for (int af = 0; af < 4; ++af)
                a[af] = *(const bf16x8*)&Xl[wr * 64 + af * 16 + li][ks * 32 + g * 8];
#pragma unroll
            for (int bi = 0; bi < 2; ++bi)
                b[bi] = *(const bf16x8*)&Wl[wc * 32 + bi * 16 + li][ks * 32 + g * 8];
#pragma unroll
            for (int af = 0; af < 4; ++af)
#pragma unroll
                for (int bi = 0; bi < 2; ++bi)
                    acc[af][bi] = mfma_bf16(a[af], b[bi], acc[af][bi]);
        }
    }
#pragma unroll
    for (int af = 0; af < 4; ++af)
#pragma unroll
        for (int bi = 0; bi < 2; ++bi)
#pragma unroll
            for (int r = 0; r < 4; ++r) {
                int mrow = mblk * 128 + wr * 64 + af * 16 + 4 * g + r;
                int ncol = nblk * 64 + wc * 32 + bi * 16 + li;
                float v = (acc[af][bi][r] + bias[ncol]) * scale;
                if (OUT_F32)
                    ((float*)batch.O[z])[(size_t)mrow * 256 + ncol] = v;
                else
                    ((__bf16*)batch.O[z])[(size_t)mrow * 256 + ncol] = (__bf16)v;
            }
}

struct AttnArgs {
    const __bf16* Q[2];
    const __bf16* K[2];
    const __bf16* V[2];
    __bf16* AO[2];
};

// Swapped-QK^T flash attention, fixed-shift softmax (no online max).
// Q pre-scaled by (1/sqrt(hd))*log2(e); QK C-init = -12 (hoisted loop-invariant
// C operand, MFMA reads C directly with D!=C -> no per-tile v_movs);
// p = exp2(s) via raw v_exp_f32 (R8-proven). Row sums via MFMA ones-B.
// K/V double-buffered in LDS with async-stage split (T14): tile t+1's global
// loads are issued before tile t's compute, so load latency hides under MFMA;
// after the post-compute barrier only ds_writes remain.
// Grid: 1024 flat blocks XCD-swizzled; 256 threads = 4 waves, 32 q rows/wave.
__global__ __launch_bounds__(256, 4)
void attn_kernel(AttnArgs args) {
    __shared__ __bf16 Kl[2][128][40];   // K tiles [s][d], padded
    __shared__ __bf16 Vt[2][32][136];   // V^T tiles [d][s], padded + XOR-swizzled
    const int fid = blockIdx.x;
    const int swz = (fid & 7) * 128 + (fid >> 3);  // 1024 -> 8 XCD chunks of 128
    const int qb = swz & 7;
    const int nh = (swz >> 3) & 63;
    const int st = swz >> 9;
    const int n = nh >> 3, h = nh & 7;
    const __bf16* __restrict__ Q = args.Q[st];
    const __bf16* __restrict__ K = args.K[st];
    const __bf16* __restrict__ V = args.V[st];
    __bf16* __restrict__ AO = args.AO[st];
    const int tid = threadIdx.x;
    const int w = tid >> 6, lane = tid & 63;
    const int q32 = lane & 31, hi = lane >> 5;

    // Q B-fragments: col = q32, k(kb) = kb*16 + 8*hi + e
    bf16x8 qf[2];
    {
        int qrow = qb * 128 + w * 32 + q32;
#pragma unroll
        for (int kb = 0; kb < 2; ++kb)
            qf[kb] = *(const bf16x8*)(Q + ((size_t)qrow * NB + n) * EMB + h * HD + kb * 16 + hi * 8);
    }

    bf16x8 ones;
#pragma unroll
    for (int j = 0; j < 8; ++j) ones[j] = (__bf16)1.0f;
    f32x16 minit;
#pragma unroll
    for (int r = 0; r < 16; ++r) minit[r] = -12.0f;  // fixed softmax shift, hoisted

    f32x16 accO, accL;
#pragma unroll
    for (int r = 0; r < 16; ++r) { accO[r] = 0.f; accL[r] = 0.f; }

    const int vsw_r = ((q32 >> 3) & 3) << 3;   // read-side Vt column swizzle

    // per-thread staging addresses (idx = tid + p*256 -> row, c8)
    const int srow0 = tid >> 2, c8s = (tid & 3) * 8;
    const int srow1 = srow0 + 64;

    bf16x8 kreg[2], vreg[2];
    // prologue: load + write tile 0
    {
        size_t g0 = ((size_t)srow0 * NB + n) * EMB + h * HD + c8s;
        size_t g1 = ((size_t)srow1 * NB + n) * EMB + h * HD + c8s;
        kreg[0] = *(const bf16x8*)(K + g0); vreg[0] = *(const bf16x8*)(V + g0);
        kreg[1] = *(const bf16x8*)(K + g1); vreg[1] = *(const bf16x8*)(V + g1);
        *(bf16x8*)&Kl[0][srow0][c8s] = kreg[0];
        *(bf16x8*)&Kl[0][srow1][c8s] = kreg[1];
#pragma unroll
        for (int j = 0; j < 8; ++j) {
            int d = c8s + j, sw = ((d >> 3) & 3) << 3;
            Vt[0][d][srow0 ^ sw] = vreg[0][j];
            Vt[0][d][srow1 ^ sw] = vreg[1][j];
        }
    }
    __syncthreads();

    for (int t = 0; t < 8; ++t) {
        const int buf = t & 1;
        if (t < 7) {   // issue next tile's loads before compute (T14)
            size_t g0 = ((size_t)((t + 1) * 128 + srow0) * NB + n) * EMB + h * HD + c8s;
            size_t g1 = ((size_t)((t + 1) * 128 + srow1) * NB + n) * EMB + h * HD + c8s;
            kreg[0] = *(const bf16x8*)(K + g0); vreg[0] = *(const bf16x8*)(V + g0);
            kreg[1] = *(const bf16x8*)(K + g1); vreg[1] = *(const bf16x8*)(V + g1);
        }

#pragma unroll
        for (int sb = 0; sb < 4; ++sb) {
            // S^T = K * Q^T - 12 : lane holds col q32, rows (r&3)+8*(r>>2)+4*hi
            bf16x8 kf0 = *(const bf16x8*)&Kl[buf][sb * 32 + q32][hi * 8];
            bf16x8 kf1 = *(const bf16x8*)&Kl[buf][sb * 32 + q32][16 + hi * 8];
            __builtin_amdgcn_s_setprio(1);
            f32x16 s = mfma32(kf0, qf[0], minit);
            s = mfma32(kf1, qf[1], s);
            __builtin_amdgcn_s_setprio(0);
            float p[16];
#pragma unroll
            for (int r = 0; r < 16; ++r) p[r] = __builtin_amdgcn_exp2f(s[r]);

            // pack P -> bf16 A-fragments; half-swap via v_permlane32_swap_b32
            bf16x8 pa[2];
#pragma unroll
            for (int ks = 0; ks < 2; ++ks) {
                unsigned x0 = pack2(p[8 * ks + 0], p[8 * ks + 1]);
                unsigned x1 = pack2(p[8 * ks + 2], p[8 * ks + 3]);
                unsigned x2 = pack2(p[8 * ks + 4], p[8 * ks + 5]);
                unsigned x3 = pack2(p[8 * ks + 6], p[8 * ks + 7]);
                permswap(x0, x2);
                permswap(x1, x3);
                union { unsigned u[4]; bf16x8 v; } cvt;
                cvt.u[0] = x0; cvt.u[1] = x1; cvt.u[2] = x2; cvt.u[3] = x3;
                pa[ks] = cvt.v;
            }
            // PV and row-sum accumulation (both in C-layout, rows = q, cols = d)
            bf16x8 vf0 = *(const bf16x8*)&Vt[buf][q32][(sb * 32 + hi * 8) ^ vsw_r];
            bf16x8 vf1 = *(const bf16x8*)&Vt[buf][q32][(sb * 32 + 16 + hi * 8) ^ vsw_r];
            __builtin_amdgcn_s_setprio(1);
            accO = mfma32(pa[0], vf0, accO);
            accL = mfma32(pa[0], ones, accL);
            accO = mfma32(pa[1], vf1, accO);
            accL = mfma32(pa[1], ones, accL);
            __builtin_amdgcn_s_setprio(0);
        }

        __syncthreads();
        if (t < 7) {   // write next tile (loads landed during compute)
            const int nbuf = buf ^ 1;
            *(bf16x8*)&Kl[nbuf][srow0][c8s] = kreg[0];
            *(bf16x8*)&Kl[nbuf][srow1][c8s] = kreg[1];
#pragma unroll
            for (int j = 0; j < 8; ++j) {
                int d = c8s + j, sw = ((d >> 3) & 3) << 3;
                Vt[nbuf][d][srow0 ^ sw] = vreg[0][j];
                Vt[nbuf][d][srow1 ^ sw] = vreg[1][j];
            }
            __syncthreads();
        }
    }

    // epilogue: out = accO / accL (identical C-layout -> no shuffles)
#pragma unroll
    for (int r = 0; r < 16; ++r) {
        int crow = (r & 3) + 8 * (r >> 2) + 4 * hi;
        int row = qb * 128 + w * 32 + crow;
        AO[((size_t)row * NB + n) * EMB + h * HD + q32] = (__bf16)(accO[r] / accL[r]);
    }
}

extern "C" void kernel_launch(void* const* d_in, const int* in_sizes, int n_in,
                              void* d_out, int out_size, void* d_ws, size_t ws_size,
                              hipStream_t stream) {
    const size_t SZ = SZ_ELEM;
    __bf16* wsb = (__bf16*)d_ws;
    __bf16* arr[8];
    for (int i = 0; i < 8; ++i) arr[i] = wsb + (size_t)i * SZ;

    // 1/sqrt(32) * log2(e): fold attention scale + exp2 conversion into Q
    const float qscale = 0.25504310349362475f;

    GemmBatch pb{};
    for (int s = 0; s < 6; ++s) {
        pb.X[s] = d_in[s];
        pb.W[s] = (const float*)d_in[6 + s];
        pb.Bv[s] = (const float*)d_in[14 + s];
        pb.O[s] = arr[s];
        pb.scale[s] = (s == 0 || s == 3) ? qscale : 1.0f;
    }
    hipLaunchKernelGGL((gemm_kernel<0, false>), dim3(256, 1, 6), dim3(256), 0, stream, pb);

    AttnArgs aa{};
    aa.Q[0] = arr[0]; aa.K[0] = arr[1]; aa.V[0] = arr[2]; aa.AO[0] = arr[6];
    aa.Q[1] = arr[3]; aa.K[1] = arr[4]; aa.V[1] = arr[5]; aa.AO[1] = arr[7];
    hipLaunchKernelGGL(attn_kernel, dim3(1024), dim3(256), 0, stream, aa);

    GemmBatch ob{};
    for (int s = 0; s < 2; ++s) {
        ob.X[s] = arr[6 + s];
        ob.W[s] = (const float*)d_in[12 + s];
        ob.Bv[s] = (const float*)d_in[20 + s];
        ob.O[s] = (float*)d_out + (size_t)s * SZ;
        ob.scale[s] = 1.0f;
    }
    hipLaunchKernelGGL((gemm_kernel<1, true>), dim3(256, 1, 2), dim3(256), 0, stream, ob);
}

// Round 10
// 73.920 us; speedup vs baseline: 1.0042x; 1.0042x over previous
//
#include <hip/hip_runtime.h>

typedef __attribute__((ext_vector_type(4))) float f32x4;
typedef __attribute__((ext_vector_type(16))) float f32x16;
typedef __attribute__((ext_vector_type(8))) __bf16 bf16x8;
typedef __attribute__((ext_vector_type(4))) __bf16 bf16x4;
typedef __attribute__((ext_vector_type(8))) unsigned short u16x8;

#define L_SEQ 1024
#define NB 8
#define EMB 256
#define NHEAD 8
#define HD 32
#define MROWS 8192  // L_SEQ * NB
#define SZ_ELEM ((size_t)MROWS * EMB)

static __device__ __forceinline__ f32x4 mfma_bf16(bf16x8 a, bf16x8 b, f32x4 c) {
    return __builtin_amdgcn_mfma_f32_16x16x32_bf16(a, b, c, 0, 0, 0);
}
static __device__ __forceinline__ f32x16 mfma32(bf16x8 a, bf16x8 b, f32x16 c) {
    return __builtin_amdgcn_mfma_f32_32x32x16_bf16(a, b, c, 0, 0, 0);
}

// Scalar bf16 pack from floats (PROVEN R1-R8; do NOT replace with
// v_cvt_pk_bf16_f32 asm — R7 failed with it: element-order mismatch).
static __device__ __forceinline__ unsigned pack2(float a, float b) {
    union { __bf16 h; unsigned short u; } lo, hi;
    lo.h = (__bf16)a; hi.h = (__bf16)b;
    return (unsigned)lo.u | ((unsigned)hi.u << 16);
}

// v_permlane32_swap_b32: a.hi-half-lanes <-> b.lo-half-lanes (R4/R6/R8-proven)
static __device__ __forceinline__ void permswap(unsigned &a, unsigned &b) {
    asm("v_permlane32_swap_b32 %0, %1" : "+v"(a), "+v"(b));
}

struct GemmBatch {
    const void* X[6];
    const float* W[6];
    const float* Bv[6];
    void* O[6];
    float scale[6];
};

// C[m,n] = (sum_k X[m,k] * W[n,k] + bias[n]) * scale
// BM=128, BN=64, BK=64, 256 threads = 4 waves (2x2), each wave 64x32.
// XMODE: 0 = f32 X, 1 = bf16 X.
template<int XMODE, bool OUT_F32>
__global__ __launch_bounds__(256, 2)
void gemm_kernel(GemmBatch batch) {
    __shared__ __bf16 Xl[128][72];
    __shared__ __bf16 Wl[64][72];
    const int z = blockIdx.z;
    const int fid = blockIdx.x;
    const int swz = (fid & 7) * 32 + (fid >> 3);   // 256 blocks -> 8 XCD chunks of 32
    const int nblk = swz & 3, mblk = swz >> 2;
    const float* __restrict__ W = batch.W[z];
    const float* __restrict__ bias = batch.Bv[z];
    const float scale = batch.scale[z];
    const int tid = threadIdx.x;
    const int w = tid >> 6, lane = tid & 63;
    const int g = lane >> 4, li = lane & 15;
    const int wr = w >> 1, wc = w & 1;

    f32x4 acc[4][2];
#pragma unroll
    for (int i = 0; i < 4; ++i)
#pragma unroll
        for (int j = 0; j < 2; ++j) acc[i][j] = f32x4{0.f, 0.f, 0.f, 0.f};

    for (int kk = 0; kk < 4; ++kk) {
        __syncthreads();
        if (XMODE == 1) {
            const __bf16* Xb = (const __bf16*)batch.X[z];
#pragma unroll
            for (int p = 0; p < 4; ++p) {
                int idx = tid + p * 256;
                int row = idx >> 3, c8 = (idx & 7) * 8;
                bf16x8 xv = *(const bf16x8*)(Xb + (size_t)(mblk * 128 + row) * 256 + kk * 64 + c8);
                *(bf16x8*)&Xl[row][c8] = xv;
            }
        } else {
            const float* Xf = (const float*)batch.X[z];
#pragma unroll
            for (int p = 0; p < 8; ++p) {
                int idx = tid + p * 256;
                int row = idx >> 4, c4 = (idx & 15) * 4;
                f32x4 xv = *(const f32x4*)(Xf + (size_t)(mblk * 128 + row) * 256 + kk * 64 + c4);
                bf16x4 bv;
#pragma unroll
                for (int j = 0; j < 4; ++j) bv[j] = (__bf16)xv[j];
                *(bf16x4*)&Xl[row][c4] = bv;
            }
        }
#pragma unroll
        for (int p = 0; p < 4; ++p) {
            int idx = tid + p * 256;
            int row = idx >> 4, c4 = (idx & 15) * 4;
            f32x4 wv = *(const f32x4*)(W + (size_t)(nblk * 64 + row) * 256 + kk * 64 + c4);
            bf16x4 bv;
#pragma unroll
            for (int j = 0; j < 4; ++j) bv[j] = (__bf16)wv[j];
            *(bf16x4*)&Wl[row][c4] = bv;
        }
        __syncthreads();
#pragma unroll
        for (int ks = 0; ks < 2; ++ks) {
            bf16x8 a[4], b[2];
#pragma unroll
            for (int af = 0; af < 4; ++af)
                a[af] = *(const bf16x8*)&Xl[wr * 64 + af * 16 + li][ks * 32 + g * 8];
#pragma unroll
            for (int bi = 0; bi < 2; ++bi)
                b[bi] = *(const bf16x8*)&Wl[wc * 32 + bi * 16 + li][ks * 32 + g * 8];
#pragma unroll
            for (int af = 0; af < 4; ++af)
#pragma unroll
                for (int bi = 0; bi < 2; ++bi)
                    acc[af][bi] = mfma_bf16(a[af], b[bi], acc[af][bi]);
        }
    }
#pragma unroll
    for (int af = 0; af < 4; ++af)
#pragma unroll
        for (int bi = 0; bi < 2; ++bi)
#pragma unroll
            for (int r = 0; r < 4; ++r) {
                int mrow = mblk * 128 + wr * 64 + af * 16 + 4 * g + r;
                int ncol = nblk * 64 + wc * 32 + bi * 16 + li;
                float v = (acc[af][bi][r] + bias[ncol]) * scale;
                if (OUT_F32)
                    ((float*)batch.O[z])[(size_t)mrow * 256 + ncol] = v;
                else
                    ((__bf16*)batch.O[z])[(size_t)mrow * 256 + ncol] = (__bf16)v;
            }
}

struct AttnArgs {
    const __bf16* Q[2];
    const __bf16* K[2];
    const __bf16* V[2];
    __bf16* AO[2];
};

// Swapped-QK^T flash attention, fixed-shift softmax (no online max).
// Q pre-scaled by (1/sqrt(hd))*log2(e); QK C-init = -12 (hoisted C operand);
// p = exp2(s) via raw v_exp_f32 (R8-proven). Row sums via MFMA ones-B.
// R10: staging diet — each thread stages two ADJACENT s-rows so V-transpose
// writes become 8 imm-offset ds_write_b32 (swizzle constant per thread) and
// K-writes 2 imm-offset b128; global K/V pointers hoisted + strided per tile.
// Single-buffered LDS (R9 dbuf was neutral: multi-block overlap already hides
// load latency). Grid: 1024 flat blocks XCD-swizzled; 4 waves, 32 q rows/wave.
__global__ __launch_bounds__(256, 4)
void attn_kernel(AttnArgs args) {
    __shared__ __bf16 Kl[128][40];   // K tile [s][d], padded
    __shared__ __bf16 Vt[32][136];   // V^T tile [d][s], padded + XOR-swizzled cols
    const int fid = blockIdx.x;
    const int swz = (fid & 7) * 128 + (fid >> 3);  // 1024 -> 8 XCD chunks of 128
    const int qb = swz & 7;
    const int nh = (swz >> 3) & 63;
    const int st = swz >> 9;
    const int n = nh >> 3, h = nh & 7;
    const __bf16* __restrict__ Q = args.Q[st];
    const __bf16* __restrict__ K = args.K[st];
    const __bf16* __restrict__ V = args.V[st];
    __bf16* __restrict__ AO = args.AO[st];
    const int tid = threadIdx.x;
    const int w = tid >> 6, lane = tid & 63;
    const int q32 = lane & 31, hi = lane >> 5;

    // Q B-fragments: col = q32, k(kb) = kb*16 + 8*hi + e
    bf16x8 qf[2];
    {
        int qrow = qb * 128 + w * 32 + q32;
#pragma unroll
        for (int kb = 0; kb < 2; ++kb)
            qf[kb] = *(const bf16x8*)(Q + ((size_t)qrow * NB + n) * EMB + h * HD + kb * 16 + hi * 8);
    }

    bf16x8 ones;
#pragma unroll
    for (int j = 0; j < 8; ++j) ones[j] = (__bf16)1.0f;
    f32x16 minit;
#pragma unroll
    for (int r = 0; r < 16; ++r) minit[r] = -12.0f;  // fixed softmax shift, hoisted

    f32x16 accO, accL;
#pragma unroll
    for (int r = 0; r < 16; ++r) { accO[r] = 0.f; accL[r] = 0.f; }

    const int vsw_r = ((q32 >> 3) & 3) << 3;   // read-side Vt column swizzle

    // staging: thread -> rows (2*r2, 2*r2+1), cols [c8s, c8s+8)
    const int r2 = tid >> 2;                  // 0..63
    const int c8s = (tid & 3) * 8;
    const int row0 = 2 * r2;                  // even
    const int vsw_w = ((c8s >> 3) & 3) << 3;  // write-side swizzle: constant/thread
    const int vcol0 = row0 ^ vsw_w;           // even (swizzle only touches bits 3,4)
    const __bf16* Kp = K + ((size_t)row0 * NB + n) * EMB + h * HD + c8s;
    const __bf16* Vp = V + ((size_t)row0 * NB + n) * EMB + h * HD + c8s;
    const size_t rstride = (size_t)NB * EMB;          // +1 s-row
    const size_t tstride = (size_t)128 * NB * EMB;    // +1 tile

    for (int t = 0; t < 8; ++t) {
        __syncthreads();
        {
            bf16x8 k0 = *(const bf16x8*)(Kp);
            bf16x8 k1 = *(const bf16x8*)(Kp + rstride);
            bf16x8 v0 = *(const bf16x8*)(Vp);
            bf16x8 v1 = *(const bf16x8*)(Vp + rstride);
            Kp += tstride; Vp += tstride;
            *(bf16x8*)&Kl[row0][c8s] = k0;
            *(bf16x8*)&Kl[row0 + 1][c8s] = k1;
            union { bf16x8 v; u16x8 u; } b0, b1;
            b0.v = v0; b1.v = v1;
#pragma unroll
            for (int j = 0; j < 8; ++j)
                *(unsigned*)&Vt[c8s + j][vcol0] = (unsigned)b0.u[j] | ((unsigned)b1.u[j] << 16);
        }
        __syncthreads();

#pragma unroll
        for (int sb = 0; sb < 4; ++sb) {
            // S^T = K * Q^T - 12 : lane holds col q32, rows (r&3)+8*(r>>2)+4*hi
            bf16x8 kf0 = *(const bf16x8*)&Kl[sb * 32 + q32][hi * 8];
            bf16x8 kf1 = *(const bf16x8*)&Kl[sb * 32 + q32][16 + hi * 8];
            __builtin_amdgcn_s_setprio(1);
            f32x16 s = mfma32(kf0, qf[0], minit);
            s = mfma32(kf1, qf[1], s);
            __builtin_amdgcn_s_setprio(0);
            float p[16];
#pragma unroll
            for (int r = 0; r < 16; ++r) p[r] = __builtin_amdgcn_exp2f(s[r]);

            // pack P -> bf16 A-fragments; half-swap via v_permlane32_swap_b32
            bf16x8 pa[2];
#pragma unroll
            for (int ks = 0; ks < 2; ++ks) {
                unsigned x0 = pack2(p[8 * ks + 0], p[8 * ks + 1]);
                unsigned x1 = pack2(p[8 * ks + 2], p[8 * ks + 3]);
                unsigned x2 = pack2(p[8 * ks + 4], p[8 * ks + 5]);
                unsigned x3 = pack2(p[8 * ks + 6], p[8 * ks + 7]);
                permswap(x0, x2);
                permswap(x1, x3);
                union { unsigned u[4]; bf16x8 v; } cvt;
                cvt.u[0] = x0; cvt.u[1] = x1; cvt.u[2] = x2; cvt.u[3] = x3;
                pa[ks] = cvt.v;
            }
            // PV and row-sum accumulation (both in C-layout, rows = q, cols = d)
            bf16x8 vf0 = *(const bf16x8*)&Vt[q32][(sb * 32 + hi * 8) ^ vsw_r];
            bf16x8 vf1 = *(const bf16x8*)&Vt[q32][(sb * 32 + 16 + hi * 8) ^ vsw_r];
            __builtin_amdgcn_s_setprio(1);
            accO = mfma32(pa[0], vf0, accO);
            accL = mfma32(pa[0], ones, accL);
            accO = mfma32(pa[1], vf1, accO);
            accL = mfma32(pa[1], ones, accL);
            __builtin_amdgcn_s_setprio(0);
        }
    }

    // epilogue: out = accO / accL (identical C-layout -> no shuffles)
#pragma unroll
    for (int r = 0; r < 16; ++r) {
        int crow = (r & 3) + 8 * (r >> 2) + 4 * hi;
        int row = qb * 128 + w * 32 + crow;
        AO[((size_t)row * NB + n) * EMB + h * HD + q32] = (__bf16)(accO[r] / accL[r]);
    }
}

extern "C" void kernel_launch(void* const* d_in, const int* in_sizes, int n_in,
                              void* d_out, int out_size, void* d_ws, size_t ws_size,
                              hipStream_t stream) {
    const size_t SZ = SZ_ELEM;
    __bf16* wsb = (__bf16*)d_ws;
    __bf16* arr[8];
    for (int i = 0; i < 8; ++i) arr[i] = wsb + (size_t)i * SZ;

    // 1/sqrt(32) * log2(e): fold attention scale + exp2 conversion into Q
    const float qscale = 0.25504310349362475f;

    GemmBatch pb{};
    for (int s = 0; s < 6; ++s) {
        pb.X[s] = d_in[s];
        pb.W[s] = (const float*)d_in[6 + s];
        pb.Bv[s] = (const float*)d_in[14 + s];
        pb.O[s] = arr[s];
        pb.scale[s] = (s == 0 || s == 3) ? qscale : 1.0f;
    }
    hipLaunchKernelGGL((gemm_kernel<0, false>), dim3(256, 1, 6), dim3(256), 0, stream, pb);

    AttnArgs aa{};
    aa.Q[0] = arr[0]; aa.K[0] = arr[1]; aa.V[0] = arr[2]; aa.AO[0] = arr[6];
    aa.Q[1] = arr[3]; aa.K[1] = arr[4]; aa.V[1] = arr[5]; aa.AO[1] = arr[7];
    hipLaunchKernelGGL(attn_kernel, dim3(1024), dim3(256), 0, stream, aa);

    GemmBatch ob{};
    for (int s = 0; s < 2; ++s) {
        ob.X[s] = arr[6 + s];
        ob.W[s] = (const float*)d_in[12 + s];
        ob.Bv[s] = (const float*)d_in[20 + s];
        ob.O[s] = (float*)d_out + (size_t)s * SZ;
        ob.scale[s] = 1.0f;
    }
    hipLaunchKernelGGL((gemm_kernel<1, true>), dim3(256, 1, 2), dim3(256), 0, stream, ob);
}

// Round 11
// 73.045 us; speedup vs baseline: 1.0162x; 1.0120x over previous
//
#include <hip/hip_runtime.h>

typedef __attribute__((ext_vector_type(4))) float f32x4;
typedef __attribute__((ext_vector_type(16))) float f32x16;
typedef __attribute__((ext_vector_type(8))) __bf16 bf16x8;
typedef __attribute__((ext_vector_type(4))) __bf16 bf16x4;
typedef __attribute__((ext_vector_type(8))) unsigned short u16x8;

#define L_SEQ 1024
#define NB 8
#define EMB 256
#define NHEAD 8
#define HD 32
#define MROWS 8192  // L_SEQ * NB
#define SZ_ELEM ((size_t)MROWS * EMB)

static __device__ __forceinline__ f32x4 mfma_bf16(bf16x8 a, bf16x8 b, f32x4 c) {
    return __builtin_amdgcn_mfma_f32_16x16x32_bf16(a, b, c, 0, 0, 0);
}
static __device__ __forceinline__ f32x16 mfma32(bf16x8 a, bf16x8 b, f32x16 c) {
    return __builtin_amdgcn_mfma_f32_32x32x16_bf16(a, b, c, 0, 0, 0);
}

// Scalar bf16 pack from floats (PROVEN R1-R8; do NOT replace with
// v_cvt_pk_bf16_f32 asm — R7 failed with it: element-order mismatch).
static __device__ __forceinline__ unsigned pack2(float a, float b) {
    union { __bf16 h; unsigned short u; } lo, hi;
    lo.h = (__bf16)a; hi.h = (__bf16)b;
    return (unsigned)lo.u | ((unsigned)hi.u << 16);
}

// v_permlane32_swap_b32: a.hi-half-lanes <-> b.lo-half-lanes (R4/R6/R8-proven)
static __device__ __forceinline__ void permswap(unsigned &a, unsigned &b) {
    asm("v_permlane32_swap_b32 %0, %1" : "+v"(a), "+v"(b));
}

struct GemmBatch {
    const void* X[6];
    const float* W[6];
    const float* Bv[6];
    void* O[6];
    float scale[6];
};

// C[m,n] = (sum_k X[m,k] * W[n,k] + bias[n]) * scale
// BM=128, BN=64, BK=64, 256 threads = 4 waves (2x2), each wave 64x32.
// XMODE: 0 = f32 X, 1 = bf16 X.
template<int XMODE, bool OUT_F32>
__global__ __launch_bounds__(256, 2)
void gemm_kernel(GemmBatch batch) {
    __shared__ __bf16 Xl[128][72];
    __shared__ __bf16 Wl[64][72];
    const int z = blockIdx.z;
    const int fid = blockIdx.x;
    const int swz = (fid & 7) * 32 + (fid >> 3);   // 256 blocks -> 8 XCD chunks of 32
    const int nblk = swz & 3, mblk = swz >> 2;
    const float* __restrict__ W = batch.W[z];
    const float* __restrict__ bias = batch.Bv[z];
    const float scale = batch.scale[z];
    const int tid = threadIdx.x;
    const int w = tid >> 6, lane = tid & 63;
    const int g = lane >> 4, li = lane & 15;
    const int wr = w >> 1, wc = w & 1;

    f32x4 acc[4][2];
#pragma unroll
    for (int i = 0; i < 4; ++i)
#pragma unroll
        for (int j = 0; j < 2; ++j) acc[i][j] = f32x4{0.f, 0.f, 0.f, 0.f};

    for (int kk = 0; kk < 4; ++kk) {
        __syncthreads();
        if (XMODE == 1) {
            const __bf16* Xb = (const __bf16*)batch.X[z];
#pragma unroll
            for (int p = 0; p < 4; ++p) {
                int idx = tid + p * 256;
                int row = idx >> 3, c8 = (idx & 7) * 8;
                bf16x8 xv = *(const bf16x8*)(Xb + (size_t)(mblk * 128 + row) * 256 + kk * 64 + c8);
                *(bf16x8*)&Xl[row][c8] = xv;
            }
        } else {
            const float* Xf = (const float*)batch.X[z];
#pragma unroll
            for (int p = 0; p < 8; ++p) {
                int idx = tid + p * 256;
                int row = idx >> 4, c4 = (idx & 15) * 4;
                f32x4 xv = *(const f32x4*)(Xf + (size_t)(mblk * 128 + row) * 256 + kk * 64 + c4);
                bf16x4 bv;
#pragma unroll
                for (int j = 0; j < 4; ++j) bv[j] = (__bf16)xv[j];
                *(bf16x4*)&Xl[row][c4] = bv;
            }
        }
#pragma unroll
        for (int p = 0; p < 4; ++p) {
            int idx = tid + p * 256;
            int row = idx >> 4, c4 = (idx & 15) * 4;
            f32x4 wv = *(const f32x4*)(W + (size_t)(nblk * 64 + row) * 256 + kk * 64 + c4);
            bf16x4 bv;
#pragma unroll
            for (int j = 0; j < 4; ++j) bv[j] = (__bf16)wv[j];
            *(bf16x4*)&Wl[row][c4] = bv;
        }
        __syncthreads();
#pragma unroll
        for (int ks = 0; ks < 2; ++ks) {
            bf16x8 a[4], b[2];
#pragma unroll
            for (int af = 0; af < 4; ++af)
                a[af] = *(const bf16x8*)&Xl[wr * 64 + af * 16 + li][ks * 32 + g * 8];
#pragma unroll
            for (int bi = 0; bi < 2; ++bi)
                b[bi] = *(const bf16x8*)&Wl[wc * 32 + bi * 16 + li][ks * 32 + g * 8];
#pragma unroll
            for (int af = 0; af < 4; ++af)
#pragma unroll
                for (int bi = 0; bi < 2; ++bi)
                    acc[af][bi] = mfma_bf16(a[af], b[bi], acc[af][bi]);
        }
    }
#pragma unroll
    for (int af = 0; af < 4; ++af)
#pragma unroll
        for (int bi = 0; bi < 2; ++bi)
#pragma unroll
            for (int r = 0; r < 4; ++r) {
                int mrow = mblk * 128 + wr * 64 + af * 16 + 4 * g + r;
                int ncol = nblk * 64 + wc * 32 + bi * 16 + li;
                float v = (acc[af][bi][r] + bias[ncol]) * scale;
                if (OUT_F32)
                    ((float*)batch.O[z])[(size_t)mrow * 256 + ncol] = v;
                else
                    ((__bf16*)batch.O[z])[(size_t)mrow * 256 + ncol] = (__bf16)v;
            }
}

struct AttnArgs {
    const __bf16* Q[2];
    const __bf16* K[2];
    const __bf16* V[2];
    __bf16* AO[2];
};

// Swapped-QK^T flash attention, fixed-shift softmax (no online max).
// Q pre-scaled by (1/sqrt(hd))*log2(e); QK C-init = -12 (hoisted C operand);
// p = exp2(s) via raw v_exp_f32 (R8-proven). Row sums via MFMA ones-B.
// R11: 2-stage sb pipeline (T15) — QK^T MFMAs of sb+1 issue BEFORE the
// exp/pack/PV finish of sb, so the transcendental-heavy softmax (VALU pipe)
// overlaps the next tile's QK (matrix pipe) within one wave. Static s_cur /
// s_next naming keeps everything in registers (rule #20).
// Grid: 1024 flat blocks XCD-swizzled; 4 waves, 32 q rows/wave.
__global__ __launch_bounds__(256, 4)
void attn_kernel(AttnArgs args) {
    __shared__ __bf16 Kl[128][40];   // K tile [s][d], padded
    __shared__ __bf16 Vt[32][136];   // V^T tile [d][s], padded + XOR-swizzled cols
    const int fid = blockIdx.x;
    const int swz = (fid & 7) * 128 + (fid >> 3);  // 1024 -> 8 XCD chunks of 128
    const int qb = swz & 7;
    const int nh = (swz >> 3) & 63;
    const int st = swz >> 9;
    const int n = nh >> 3, h = nh & 7;
    const __bf16* __restrict__ Q = args.Q[st];
    const __bf16* __restrict__ K = args.K[st];
    const __bf16* __restrict__ V = args.V[st];
    __bf16* __restrict__ AO = args.AO[st];
    const int tid = threadIdx.x;
    const int w = tid >> 6, lane = tid & 63;
    const int q32 = lane & 31, hi = lane >> 5;

    // Q B-fragments: col = q32, k(kb) = kb*16 + 8*hi + e
    bf16x8 qf[2];
    {
        int qrow = qb * 128 + w * 32 + q32;
#pragma unroll
        for (int kb = 0; kb < 2; ++kb)
            qf[kb] = *(const bf16x8*)(Q + ((size_t)qrow * NB + n) * EMB + h * HD + kb * 16 + hi * 8);
    }

    bf16x8 ones;
#pragma unroll
    for (int j = 0; j < 8; ++j) ones[j] = (__bf16)1.0f;
    f32x16 minit;
#pragma unroll
    for (int r = 0; r < 16; ++r) minit[r] = -12.0f;  // fixed softmax shift, hoisted

    f32x16 accO, accL;
#pragma unroll
    for (int r = 0; r < 16; ++r) { accO[r] = 0.f; accL[r] = 0.f; }

    const int vsw_r = ((q32 >> 3) & 3) << 3;   // read-side Vt column swizzle

    // staging: thread -> rows (2*r2, 2*r2+1), cols [c8s, c8s+8) (R10 layout)
    const int r2 = tid >> 2;
    const int c8s = (tid & 3) * 8;
    const int row0 = 2 * r2;
    const int vsw_w = ((c8s >> 3) & 3) << 3;
    const int vcol0 = row0 ^ vsw_w;
    const __bf16* Kp = K + ((size_t)row0 * NB + n) * EMB + h * HD + c8s;
    const __bf16* Vp = V + ((size_t)row0 * NB + n) * EMB + h * HD + c8s;
    const size_t rstride = (size_t)NB * EMB;
    const size_t tstride = (size_t)128 * NB * EMB;

    for (int t = 0; t < 8; ++t) {
        __syncthreads();
        {
            bf16x8 k0 = *(const bf16x8*)(Kp);
            bf16x8 k1 = *(const bf16x8*)(Kp + rstride);
            bf16x8 v0 = *(const bf16x8*)(Vp);
            bf16x8 v1 = *(const bf16x8*)(Vp + rstride);
            Kp += tstride; Vp += tstride;
            *(bf16x8*)&Kl[row0][c8s] = k0;
            *(bf16x8*)&Kl[row0 + 1][c8s] = k1;
            union { bf16x8 v; u16x8 u; } b0, b1;
            b0.v = v0; b1.v = v1;
#pragma unroll
            for (int j = 0; j < 8; ++j)
                *(unsigned*)&Vt[c8s + j][vcol0] = (unsigned)b0.u[j] | ((unsigned)b1.u[j] << 16);
        }
        __syncthreads();

        // 2-stage pipeline: QK(sb+1) issues before softmax-finish(sb)
        f32x16 s_cur;
        {
            bf16x8 kf0 = *(const bf16x8*)&Kl[q32][hi * 8];
            bf16x8 kf1 = *(const bf16x8*)&Kl[q32][16 + hi * 8];
            s_cur = mfma32(kf0, qf[0], minit);
            s_cur = mfma32(kf1, qf[1], s_cur);
        }
#pragma unroll
        for (int sb = 0; sb < 4; ++sb) {
            f32x16 s_next;
            if (sb < 3) {
                bf16x8 nkf0 = *(const bf16x8*)&Kl[(sb + 1) * 32 + q32][hi * 8];
                bf16x8 nkf1 = *(const bf16x8*)&Kl[(sb + 1) * 32 + q32][16 + hi * 8];
                s_next = mfma32(nkf0, qf[0], minit);
                s_next = mfma32(nkf1, qf[1], s_next);
            }
            // softmax-finish for s_cur (VALU) — overlaps s_next's QK (matrix pipe)
            float p[16];
#pragma unroll
            for (int r = 0; r < 16; ++r) p[r] = __builtin_amdgcn_exp2f(s_cur[r]);

            bf16x8 pa[2];
#pragma unroll
            for (int ks = 0; ks < 2; ++ks) {
                unsigned x0 = pack2(p[8 * ks + 0], p[8 * ks + 1]);
                unsigned x1 = pack2(p[8 * ks + 2], p[8 * ks + 3]);
                unsigned x2 = pack2(p[8 * ks + 4], p[8 * ks + 5]);
                unsigned x3 = pack2(p[8 * ks + 6], p[8 * ks + 7]);
                permswap(x0, x2);
                permswap(x1, x3);
                union { unsigned u[4]; bf16x8 v; } cvt;
                cvt.u[0] = x0; cvt.u[1] = x1; cvt.u[2] = x2; cvt.u[3] = x3;
                pa[ks] = cvt.v;
            }
            bf16x8 vf0 = *(const bf16x8*)&Vt[q32][(sb * 32 + hi * 8) ^ vsw_r];
            bf16x8 vf1 = *(const bf16x8*)&Vt[q32][(sb * 32 + 16 + hi * 8) ^ vsw_r];
            __builtin_amdgcn_s_setprio(1);
            accO = mfma32(pa[0], vf0, accO);
            accL = mfma32(pa[0], ones, accL);
            accO = mfma32(pa[1], vf1, accO);
            accL = mfma32(pa[1], ones, accL);
            __builtin_amdgcn_s_setprio(0);
            if (sb < 3) s_cur = s_next;
        }
    }

    // epilogue: out = accO / accL (identical C-layout -> no shuffles)
#pragma unroll
    for (int r = 0; r < 16; ++r) {
        int crow = (r & 3) + 8 * (r >> 2) + 4 * hi;
        int row = qb * 128 + w * 32 + crow;
        AO[((size_t)row * NB + n) * EMB + h * HD + q32] = (__bf16)(accO[r] / accL[r]);
    }
}

extern "C" void kernel_launch(void* const* d_in, const int* in_sizes, int n_in,
                              void* d_out, int out_size, void* d_ws, size_t ws_size,
                              hipStream_t stream) {
    const size_t SZ = SZ_ELEM;
    __bf16* wsb = (__bf16*)d_ws;
    __bf16* arr[8];
    for (int i = 0; i < 8; ++i) arr[i] = wsb + (size_t)i * SZ;

    // 1/sqrt(32) * log2(e): fold attention scale + exp2 conversion into Q
    const float qscale = 0.25504310349362475f;

    GemmBatch pb{};
    for (int s = 0; s < 6; ++s) {
        pb.X[s] = d_in[s];
        pb.W[s] = (const float*)d_in[6 + s];
        pb.Bv[s] = (const float*)d_in[14 + s];
        pb.O[s] = arr[s];
        pb.scale[s] = (s == 0 || s == 3) ? qscale : 1.0f;
    }
    hipLaunchKernelGGL((gemm_kernel<0, false>), dim3(256, 1, 6), dim3(256), 0, stream, pb);

    AttnArgs aa{};
    aa.Q[0] = arr[0]; aa.K[0] = arr[1]; aa.V[0] = arr[2]; aa.AO[0] = arr[6];
    aa.Q[1] = arr[3]; aa.K[1] = arr[4]; aa.V[1] = arr[5]; aa.AO[1] = arr[7];
    hipLaunchKernelGGL(attn_kernel, dim3(1024), dim3(256), 0, stream, aa);

    GemmBatch ob{};
    for (int s = 0; s < 2; ++s) {
        ob.X[s] = arr[6 + s];
        ob.W[s] = (const float*)d_in[12 + s];
        ob.Bv[s] = (const float*)d_in[20 + s];
        ob.O[s] = (float*)d_out + (size_t)s * SZ;
        ob.scale[s] = 1.0f;
    }
    hipLaunchKernelGGL((gemm_kernel<1, true>), dim3(256, 1, 2), dim3(256), 0, stream, ob);
}

// Round 13
// 71.919 us; speedup vs baseline: 1.0321x; 1.0157x over previous
//
#include <hip/hip_runtime.h>

typedef __attribute__((ext_vector_type(4))) float f32x4;
typedef __attribute__((ext_vector_type(16))) float f32x16;
typedef __attribute__((ext_vector_type(8))) __bf16 bf16x8;
typedef __attribute__((ext_vector_type(4))) __bf16 bf16x4;
typedef __attribute__((ext_vector_type(8))) unsigned short u16x8;

#define L_SEQ 1024
#define NB 8
#define EMB 256
#define NHEAD 8
#define HD 32
#define MROWS 8192  // L_SEQ * NB
#define SZ_ELEM ((size_t)MROWS * EMB)

static __device__ __forceinline__ f32x4 mfma_bf16(bf16x8 a, bf16x8 b, f32x4 c) {
    return __builtin_amdgcn_mfma_f32_16x16x32_bf16(a, b, c, 0, 0, 0);
}
static __device__ __forceinline__ f32x16 mfma32(bf16x8 a, bf16x8 b, f32x16 c) {
    return __builtin_amdgcn_mfma_f32_32x32x16_bf16(a, b, c, 0, 0, 0);
}

// Scalar bf16 pack from floats (PROVEN R1-R11; do NOT replace with
// v_cvt_pk_bf16_f32 asm — R7 failed with it: element-order mismatch).
static __device__ __forceinline__ unsigned pack2(float a, float b) {
    union { __bf16 h; unsigned short u; } lo, hi;
    lo.h = (__bf16)a; hi.h = (__bf16)b;
    return (unsigned)lo.u | ((unsigned)hi.u << 16);
}

// v_permlane32_swap_b32: a.hi-half-lanes <-> b.lo-half-lanes (R4-R11-proven)
static __device__ __forceinline__ void permswap(unsigned &a, unsigned &b) {
    asm("v_permlane32_swap_b32 %0, %1" : "+v"(a), "+v"(b));
}

struct GemmBatch {
    const void* X[6];
    const float* W[6];
    const float* Bv[6];
    void* O[6];
    float scale[6];
};

// C[m,n] = (sum_k X[m,k] * W[n,k] + bias[n]) * scale
// BM=128, BN=64, BK=64, 256 threads = 4 waves (2x2), each wave 64x32.
// XMODE: 0 = f32 X, 1 = bf16 X.
template<int XMODE, bool OUT_F32>
__global__ __launch_bounds__(256, 2)
void gemm_kernel(GemmBatch batch) {
    __shared__ __bf16 Xl[128][72];
    __shared__ __bf16 Wl[64][72];
    const int z = blockIdx.z;
    const int fid = blockIdx.x;
    const int swz = (fid & 7) * 32 + (fid >> 3);   // 256 blocks -> 8 XCD chunks of 32
    const int nblk = swz & 3, mblk = swz >> 2;
    const float* __restrict__ W = batch.W[z];
    const float* __restrict__ bias = batch.Bv[z];
    const float scale = batch.scale[z];
    const int tid = threadIdx.x;
    const int w = tid >> 6, lane = tid & 63;
    const int g = lane >> 4, li = lane & 15;
    const int wr = w >> 1, wc = w & 1;

    f32x4 acc[4][2];
#pragma unroll
    for (int i = 0; i < 4; ++i)
#pragma unroll
        for (int j = 0; j < 2; ++j) acc[i][j] = f32x4{0.f, 0.f, 0.f, 0.f};

    for (int kk = 0; kk < 4; ++kk) {
        __syncthreads();
        if (XMODE == 1) {
            const __bf16* Xb = (const __bf16*)batch.X[z];
#pragma unroll
            for (int p = 0; p < 4; ++p) {
                int idx = tid + p * 256;
                int row = idx >> 3, c8 = (idx & 7) * 8;
                bf16x8 xv = *(const bf16x8*)(Xb + (size_t)(mblk * 128 + row) * 256 + kk * 64 + c8);
                *(bf16x8*)&Xl[row][c8] = xv;
            }
        } else {
            const float* Xf = (const float*)batch.X[z];
#pragma unroll
            for (int p = 0; p < 8; ++p) {
                int idx = tid + p * 256;
                int row = idx >> 4, c4 = (idx & 15) * 4;
                f32x4 xv = *(const f32x4*)(Xf + (size_t)(mblk * 128 + row) * 256 + kk * 64 + c4);
                bf16x4 bv;
#pragma unroll
                for (int j = 0; j < 4; ++j) bv[j] = (__bf16)xv[j];
                *(bf16x4*)&Xl[row][c4] = bv;
            }
        }
#pragma unroll
        for (int p = 0; p < 4; ++p) {
            int idx = tid + p * 256;
            int row = idx >> 4, c4 = (idx & 15) * 4;
            f32x4 wv = *(const f32x4*)(W + (size_t)(nblk * 64 + row) * 256 + kk * 64 + c4);
            bf16x4 bv;
#pragma unroll
            for (int j = 0; j < 4; ++j) bv[j] = (__bf16)wv[j];
            *(bf16x4*)&Wl[row][c4] = bv;
        }
        __syncthreads();
#pragma unroll
        for (int ks = 0; ks < 2; ++ks) {
            bf16x8 a[4], b[2];
#pragma unroll
            for (int af = 0; af < 4; ++af)
                a[af] = *(const bf16x8*)&Xl[wr * 64 + af * 16 + li][ks * 32 + g * 8];
#pragma unroll
            for (int bi = 0; bi < 2; ++bi)
                b[bi] = *(const bf16x8*)&Wl[wc * 32 + bi * 16 + li][ks * 32 + g * 8];
#pragma unroll
            for (int af = 0; af < 4; ++af)
#pragma unroll
                for (int bi = 0; bi < 2; ++bi)
                    acc[af][bi] = mfma_bf16(a[af], b[bi], acc[af][bi]);
        }
    }
#pragma unroll
    for (int af = 0; af < 4; ++af)
#pragma unroll
        for (int bi = 0; bi < 2; ++bi)
#pragma unroll
            for (int r = 0; r < 4; ++r) {
                int mrow = mblk * 128 + wr * 64 + af * 16 + 4 * g + r;
                int ncol = nblk * 64 + wc * 32 + bi * 16 + li;
                float v = (acc[af][bi][r] + bias[ncol]) * scale;
                if (OUT_F32)
                    ((float*)batch.O[z])[(size_t)mrow * 256 + ncol] = v;
                else
                    ((__bf16*)batch.O[z])[(size_t)mrow * 256 + ncol] = (__bf16)v;
            }
}

struct AttnArgs {
    const __bf16* Q[2];
    const __bf16* K[2];
    const __bf16* V[2];
    __bf16* AO[2];
};

// Swapped-QK^T flash attention, fixed-shift softmax (no online max).
// Q pre-scaled by (1/sqrt(hd))*log2(e); QK C-init = -12 (hoisted C operand);
// p = exp2(s) via raw v_exp_f32 (R8-proven). Row sums via MFMA ones-B.
// R13: KVBLK=256, 8-wave blocks (512 threads, 256 q-rows). Halves barrier
// phases (4 staging phases) and chip-wide staging volume (512 blocks x 4
// tiles). Proven 2-barrier-per-tile pattern (R12's 1-barrier dbuf FAILED —
// do not reattempt). Keeps R11's 2-stage sb pipeline and R10 paired-row
// staging. Grid: 512 flat blocks XCD-swizzled; 8 waves, 32 q rows/wave.
__global__ __launch_bounds__(512, 4)
void attn_kernel(AttnArgs args) {
    __shared__ __bf16 Kl[256][40];   // K tile [s][d], padded
    __shared__ __bf16 Vt[32][264];   // V^T tile [d][s], padded + XOR-swizzled cols
    const int fid = blockIdx.x;
    const int swz = (fid & 7) * 64 + (fid >> 3);   // 512 -> 8 XCD chunks of 64
    const int qb = swz & 3;
    const int nh = (swz >> 2) & 63;
    const int st = swz >> 8;
    const int n = nh >> 3, h = nh & 7;
    const __bf16* __restrict__ Q = args.Q[st];
    const __bf16* __restrict__ K = args.K[st];
    const __bf16* __restrict__ V = args.V[st];
    __bf16* __restrict__ AO = args.AO[st];
    const int tid = threadIdx.x;
    const int w = tid >> 6, lane = tid & 63;
    const int q32 = lane & 31, hi = lane >> 5;

    // Q B-fragments: col = q32, k(kb) = kb*16 + 8*hi + e
    bf16x8 qf[2];
    {
        int qrow = qb * 256 + w * 32 + q32;
#pragma unroll
        for (int kb = 0; kb < 2; ++kb)
            qf[kb] = *(const bf16x8*)(Q + ((size_t)qrow * NB + n) * EMB + h * HD + kb * 16 + hi * 8);
    }

    bf16x8 ones;
#pragma unroll
    for (int j = 0; j < 8; ++j) ones[j] = (__bf16)1.0f;
    f32x16 minit;
#pragma unroll
    for (int r = 0; r < 16; ++r) minit[r] = -12.0f;  // fixed softmax shift, hoisted

    f32x16 accO, accL;
#pragma unroll
    for (int r = 0; r < 16; ++r) { accO[r] = 0.f; accL[r] = 0.f; }

    const int vsw_r = ((q32 >> 3) & 3) << 3;   // read-side Vt column swizzle

    // staging: thread -> rows (2*r2, 2*r2+1) of the 256-row tile, cols [c8s, c8s+8)
    const int r2 = tid >> 2;                  // 0..127
    const int c8s = (tid & 3) * 8;
    const int row0 = 2 * r2;                  // 0..254, even
    const int vsw_w = ((c8s >> 3) & 3) << 3;  // write-side swizzle: constant/thread
    const int vcol0 = row0 ^ vsw_w;           // stays in [0,255] (flips bits 3,4)
    const __bf16* Kp = K + ((size_t)row0 * NB + n) * EMB + h * HD + c8s;
    const __bf16* Vp = V + ((size_t)row0 * NB + n) * EMB + h * HD + c8s;
    const size_t rstride = (size_t)NB * EMB;          // +1 s-row
    const size_t tstride = (size_t)256 * NB * EMB;    // +1 tile (256 rows)

    for (int t = 0; t < 4; ++t) {
        __syncthreads();
        {
            bf16x8 k0 = *(const bf16x8*)(Kp);
            bf16x8 k1 = *(const bf16x8*)(Kp + rstride);
            bf16x8 v0 = *(const bf16x8*)(Vp);
            bf16x8 v1 = *(const bf16x8*)(Vp + rstride);
            Kp += tstride; Vp += tstride;
            *(bf16x8*)&Kl[row0][c8s] = k0;
            *(bf16x8*)&Kl[row0 + 1][c8s] = k1;
            union { bf16x8 v; u16x8 u; } b0, b1;
            b0.v = v0; b1.v = v1;
#pragma unroll
            for (int j = 0; j < 8; ++j)
                *(unsigned*)&Vt[c8s + j][vcol0] = (unsigned)b0.u[j] | ((unsigned)b1.u[j] << 16);
        }
        __syncthreads();

        // 2-stage pipeline: QK(sb+1) issues before softmax-finish(sb)
        f32x16 s_cur;
        {
            bf16x8 kf0 = *(const bf16x8*)&Kl[q32][hi * 8];
            bf16x8 kf1 = *(const bf16x8*)&Kl[q32][16 + hi * 8];
            s_cur = mfma32(kf0, qf[0], minit);
            s_cur = mfma32(kf1, qf[1], s_cur);
        }
#pragma unroll
        for (int sb = 0; sb < 8; ++sb) {
            f32x16 s_next;
            if (sb < 7) {
                bf16x8 nkf0 = *(const bf16x8*)&Kl[(sb + 1) * 32 + q32][hi * 8];
                bf16x8 nkf1 = *(const bf16x8*)&Kl[(sb + 1) * 32 + q32][16 + hi * 8];
                s_next = mfma32(nkf0, qf[0], minit);
                s_next = mfma32(nkf1, qf[1], s_next);
            }
            // softmax-finish for s_cur (VALU) — overlaps s_next's QK (matrix pipe)
            float p[16];
#pragma unroll
            for (int r = 0; r < 16; ++r) p[r] = __builtin_amdgcn_exp2f(s_cur[r]);

            bf16x8 pa[2];
#pragma unroll
            for (int ks = 0; ks < 2; ++ks) {
                unsigned x0 = pack2(p[8 * ks + 0], p[8 * ks + 1]);
                unsigned x1 = pack2(p[8 * ks + 2], p[8 * ks + 3]);
                unsigned x2 = pack2(p[8 * ks + 4], p[8 * ks + 5]);
                unsigned x3 = pack2(p[8 * ks + 6], p[8 * ks + 7]);
                permswap(x0, x2);
                permswap(x1, x3);
                union { unsigned u[4]; bf16x8 v; } cvt;
                cvt.u[0] = x0; cvt.u[1] = x1; cvt.u[2] = x2; cvt.u[3] = x3;
                pa[ks] = cvt.v;
            }
            bf16x8 vf0 = *(const bf16x8*)&Vt[q32][(sb * 32 + hi * 8) ^ vsw_r];
            bf16x8 vf1 = *(const bf16x8*)&Vt[q32][(sb * 32 + 16 + hi * 8) ^ vsw_r];
            __builtin_amdgcn_s_setprio(1);
            accO = mfma32(pa[0], vf0, accO);
            accL = mfma32(pa[0], ones, accL);
            accO = mfma32(pa[1], vf1, accO);
            accL = mfma32(pa[1], ones, accL);
            __builtin_amdgcn_s_setprio(0);
            if (sb < 7) s_cur = s_next;
        }
    }

    // epilogue: out = accO / accL (identical C-layout -> no shuffles)
#pragma unroll
    for (int r = 0; r < 16; ++r) {
        int crow = (r & 3) + 8 * (r >> 2) + 4 * hi;
        int row = qb * 256 + w * 32 + crow;
        AO[((size_t)row * NB + n) * EMB + h * HD + q32] = (__bf16)(accO[r] / accL[r]);
    }
}

extern "C" void kernel_launch(void* const* d_in, const int* in_sizes, int n_in,
                              void* d_out, int out_size, void* d_ws, size_t ws_size,
                              hipStream_t stream) {
    const size_t SZ = SZ_ELEM;
    __bf16* wsb = (__bf16*)d_ws;
    __bf16* arr[8];
    for (int i = 0; i < 8; ++i) arr[i] = wsb + (size_t)i * SZ;

    // 1/sqrt(32) * log2(e): fold attention scale + exp2 conversion into Q
    const float qscale = 0.25504310349362475f;

    GemmBatch pb{};
    for (int s = 0; s < 6; ++s) {
        pb.X[s] = d_in[s];
        pb.W[s] = (const float*)d_in[6 + s];
        pb.Bv[s] = (const float*)d_in[14 + s];
        pb.O[s] = arr[s];
        pb.scale[s] = (s == 0 || s == 3) ? qscale : 1.0f;
    }
    hipLaunchKernelGGL((gemm_kernel<0, false>), dim3(256, 1, 6), dim3(256), 0, stream, pb);

    AttnArgs aa{};
    aa.Q[0] = arr[0]; aa.K[0] = arr[1]; aa.V[0] = arr[2]; aa.AO[0] = arr[6];
    aa.Q[1] = arr[3]; aa.K[1] = arr[4]; aa.V[1] = arr[5]; aa.AO[1] = arr[7];
    hipLaunchKernelGGL(attn_kernel, dim3(512), dim3(512), 0, stream, aa);

    GemmBatch ob{};
    for (int s = 0; s < 2; ++s) {
        ob.X[s] = arr[6 + s];
        ob.W[s] = (const float*)d_in[12 + s];
        ob.Bv[s] = (const float*)d_in[20 + s];
        ob.O[s] = (float*)d_out + (size_t)s * SZ;
        ob.scale[s] = 1.0f;
    }
    hipLaunchKernelGGL((gemm_kernel<1, true>), dim3(256, 1, 2), dim3(256), 0, stream, ob);
}